// Round 13
// baseline (68.114 us; speedup 1.0000x reference)
//
#include <hip/hip_runtime.h>
#include <hip/hip_bf16.h>

// Bahdanau additive attention, MI355X.  B=8, TE=TD=256, HE=HD=512.
// d_in (f32): enc [B,TE,H], dec [B,TD,H], W_a [H,H], U_a [H,H], V_a [H,1]
// d_out (f32): c [B,TD,H] | e [B,TD,TE]
//
// Math: tanh(x) = 1 - 2/(1+e^{2x}).  score = Sv - 2*A,
// A[d,t] = sum_k Va[k]/(1 + EW[t,k]*EU[d,k]),  EW = exp2(clamp(2log2e*enc@Wa,±15)).
// Sv const over t -> dropped; softmax over min(A), -2 folded into exp2 const.
// R13: same 2-kernel plan as R12 but fused grid 256->512 blocks (d-stripe 4):
//      2 blocks/CU = 4 waves/SIMD. R12 PMC: VALUBusy 48%, occ 20% -> stall-bound
//      at 2 waves/SIMD; work per element is already near-minimal (3.5 VALU).
// ws (10MB): EW4 4M | EU 4M | encT 2M

#define BB  8
#define TEE 256
#define TDD 256
#define HH  512
#define C2LOG2E 2.8853900817779268f   // 2*log2(e)

typedef __attribute__((ext_vector_type(8))) short  short8;
typedef __attribute__((ext_vector_type(4))) float  floatx4;

__device__ __forceinline__ unsigned short f2bf(float f) {
  __hip_bfloat16 h = __float2bfloat16(f);      // RNE
  return __builtin_bit_cast(unsigned short, h);
}

// ---------------- K1: proj -> EW4 (transposed) / EU (row-major) + encT ----------------
// grid 768 x 256thr: blocks 0..255 EW4, 256..511 EU, 512..767 encT.
__global__ __launch_bounds__(256) void prep_proj(
    const float* __restrict__ enc, const float* __restrict__ dec,
    const float* __restrict__ Wa,  const float* __restrict__ Ua,
    float* __restrict__ EW4, float* __restrict__ EU,
    unsigned short* __restrict__ encT)
{
  __shared__ float tile[64][68];
  const int bid = blockIdx.x;
  const int tid = threadIdx.x;

  if (bid < 512) {
    const int side = bid >> 8;               // 0 = EW, 1 = EU
    const int lb = bid & 255;
    const float* X = side ? dec : enc;
    const float* W = side ? Ua  : Wa;
    const int lane = tid & 63, w = tid >> 6;
    const int m0b = (lb >> 3) * 64;          // block m-base (64 rows)
    const int m0 = m0b + w * 16;             // wave's 16 rows
    const int n0 = (lb & 7) * 64;
    const int r15 = lane & 15, g = lane >> 4;

    floatx4 acc[4] = {{0.f,0.f,0.f,0.f},{0.f,0.f,0.f,0.f},
                      {0.f,0.f,0.f,0.f},{0.f,0.f,0.f,0.f}};
    const float* ap = X + (size_t)(m0 + r15) * HH + g * 8;

    for (int k0 = 0; k0 < HH; k0 += 32) {
      float4 a0 = *(const float4*)(ap + k0);
      float4 a1 = *(const float4*)(ap + k0 + 4);
      short8 a;                               // 2log2e folded into A side
      a[0]=(short)f2bf(a0.x*C2LOG2E); a[1]=(short)f2bf(a0.y*C2LOG2E);
      a[2]=(short)f2bf(a0.z*C2LOG2E); a[3]=(short)f2bf(a0.w*C2LOG2E);
      a[4]=(short)f2bf(a1.x*C2LOG2E); a[5]=(short)f2bf(a1.y*C2LOG2E);
      a[6]=(short)f2bf(a1.z*C2LOG2E); a[7]=(short)f2bf(a1.w*C2LOG2E);
      const float* wrow = W + (size_t)(k0 + g * 8) * HH + n0 + r15;
      #pragma unroll
      for (int nt = 0; nt < 4; ++nt) {
        short8 bv;
        #pragma unroll
        for (int j = 0; j < 8; ++j) bv[j] = (short)f2bf(wrow[(size_t)j * HH + nt * 16]);
        acc[nt] = __builtin_amdgcn_mfma_f32_16x16x32_bf16(a, bv, acc[nt], 0, 0, 0);
      }
    }
    // D: col = lane&15, row = (lane>>4)*4 + reg  [m89-verified]
    if (side == 1) {
      // EU: direct row-major [d][k] write
      #pragma unroll
      for (int nt = 0; nt < 4; ++nt) {
        float* yp = EU + (size_t)(m0 + g * 4) * HH + n0 + nt * 16 + r15;
        #pragma unroll
        for (int r = 0; r < 4; ++r) {
          float v = fminf(fmaxf(acc[nt][r], -15.f), 15.f);
          yp[(size_t)r * HH] = __builtin_amdgcn_exp2f(v);
        }
      }
    } else {
      // EW: exp2 -> LDS tile -> transposed coalesced write to EW4
      #pragma unroll
      for (int nt = 0; nt < 4; ++nt) {
        #pragma unroll
        for (int r = 0; r < 4; ++r) {
          float v = fminf(fmaxf(acc[nt][r], -15.f), 15.f);
          tile[w * 16 + g * 4 + r][nt * 16 + r15] = __builtin_amdgcn_exp2f(v);
        }
      }
      __syncthreads();
      // EW4 elem (k,t): b*131072 + (k>>2)*1024 + t*4 + (k&3)
      #pragma unroll
      for (int i = 0; i < 4; ++i) {
        const int cell = i * 256 + tid;        // 1024 cells = 64 t x 16 k4
        const int tl  = cell & 63;
        const int k4l = cell >> 6;
        const int m   = m0b + tl;
        const int b   = m >> 8, t = m & 255;
        const int k4  = (n0 >> 2) + k4l;
        float4 val = *(const float4*)&tile[tl][k4l * 4];
        *(float4*)(EW4 + (size_t)b * 131072 + (size_t)k4 * 1024 + t * 4) = val;
      }
    }
  } else {
    // encT[b][h][t] = bf16(enc[b][t][h]); 256 blocks: 8 b x 8 h-tiles x 4 t-tiles
    const int idx = bid - 512;
    const int b  = idx >> 5;
    const int h0 = ((idx >> 2) & 7) * 64;
    const int t0 = (idx & 3) * 64;
    const int c = tid & 63, r4 = tid >> 6;
    #pragma unroll
    for (int i = 0; i < 16; ++i) {
      int tr = i * 4 + r4;
      tile[tr][c] = enc[((size_t)b * TEE + t0 + tr) * HH + h0 + c];
    }
    __syncthreads();
    #pragma unroll
    for (int i = 0; i < 16; ++i) {
      int hr = i * 4 + r4;
      encT[((size_t)b * HH + h0 + hr) * TEE + t0 + c] = f2bf(tile[c][hr]);
    }
  }
}

// ---------------- K2: score tree + softmax + e + ctx MFMA, fused ----------------
// grid 512 = 8 b x 64 d-stripes of 4; block 512 thr = 8 waves (2 blocks/CU).
// thread = (t = tid&255, kh = tid>>8 k-half). acc[4] over d.
__global__ __launch_bounds__(512, 4) void fused(
    const float* __restrict__ EW4, const float* __restrict__ EU,
    const float* __restrict__ Va, const unsigned short* __restrict__ encT,
    float* __restrict__ c_out, float* __restrict__ e_out)
{
  __shared__ float euL[4][512];            // 8 KB
  __shared__ float As[4][260];             // 4.2 KB
  __shared__ unsigned short pe[4][264];    // 2.1 KB

  const int bid = blockIdx.x;
  const int b  = bid >> 6;
  const int d0 = (bid & 63) * 4;
  const int tid = threadIdx.x;
  const int t  = tid & 255;
  const int kh = tid >> 8;                 // k-half 0/1

  // stage EU rows d0..d0+3 (coalesced)
  {
    const int dr = tid >> 7, kk = (tid & 127) * 4;
    const float* src = EU + ((size_t)(b * TDD) + d0 + dr) * HH + kk;
    *(float4*)&euL[dr][kk] = *(const float4*)(src);
  }
  __syncthreads();

  // ---- score: 4-way rcp tree over this thread's k-half, one-deep ew prefetch
  float acc[4] = {};
  const float* ewp = EW4 + (size_t)b * 131072 + (size_t)kh * 64 * 1024 + t * 4;
  const float* vap = Va + kh * 256;
  const int kb = kh * 256;

  float4 ew = *(const float4*)(ewp);
  #pragma unroll 4
  for (int kg = 0; kg < 64; ++kg) {
    float4 ew_n;
    if (kg + 1 < 64) ew_n = *(const float4*)(ewp + (size_t)(kg + 1) * 1024);
    float4 v = *(const float4*)(vap + kg * 4);             // wave-uniform
    #pragma unroll
    for (int d = 0; d < 4; ++d) {
      float4 u = *(const float4*)&euL[d][kb + kg * 4];     // broadcast
      float A1 = fmaf(ew.x, u.x, 1.0f);
      float B1 = fmaf(ew.y, u.y, 1.0f);
      float C1 = fmaf(ew.z, u.z, 1.0f);
      float D1 = fmaf(ew.w, u.w, 1.0f);
      float dab = A1 * B1;
      float nab = fmaf(v.x, B1, v.y * A1);
      float dcd = C1 * D1;
      float ncd = fmaf(v.z, D1, v.w * C1);
      float den = dab * dcd;
      float num = fmaf(nab, dcd, ncd * dab);
      acc[d] = fmaf(num, __builtin_amdgcn_rcpf(den), acc[d]);
    }
    ew = ew_n;
  }

  // combine k-halves in LDS
  if (kh == 0) {
    #pragma unroll
    for (int d = 0; d < 4; ++d) As[d][t] = acc[d];
  }
  __syncthreads();
  if (kh == 1) {
    #pragma unroll
    for (int d = 0; d < 4; ++d) As[d][t] += acc[d];
  }
  __syncthreads();

  // ---- softmax: waves 0..3 own d-row w
  const int w = tid >> 6, lane = tid & 63;
  if (w < 4) {
    float4 x = *(const float4*)&As[w][lane * 4];
    float m = fminf(fminf(x.x, x.y), fminf(x.z, x.w));
    #pragma unroll
    for (int off = 32; off; off >>= 1) m = fminf(m, __shfl_xor(m, off));
    float p0 = __builtin_amdgcn_exp2f(C2LOG2E * (m - x.x));
    float p1 = __builtin_amdgcn_exp2f(C2LOG2E * (m - x.y));
    float p2 = __builtin_amdgcn_exp2f(C2LOG2E * (m - x.z));
    float p3 = __builtin_amdgcn_exp2f(C2LOG2E * (m - x.w));
    float s = (p0 + p1) + (p2 + p3);
    #pragma unroll
    for (int off = 32; off; off >>= 1) s += __shfl_xor(s, off);
    float r = __builtin_amdgcn_rcpf(s);
    float4 ev = {p0 * r, p1 * r, p2 * r, p3 * r};
    *(float4*)(e_out + ((size_t)(b * TDD) + d0 + w) * TEE + lane * 4) = ev;
    *(ushort2*)&pe[w][lane * 4]     = make_ushort2(f2bf(ev.x), f2bf(ev.y));
    *(ushort2*)&pe[w][lane * 4 + 2] = make_ushort2(f2bf(ev.z), f2bf(ev.w));
  }
  __syncthreads();

  // ---- ctx: wave w covers h = w*64 .. +64 (4 col-tiles); A rows 4..15 zero
  const int r15 = lane & 15, g = lane >> 4;
  const int hw = w * 64;
  floatx4 ca[4] = {{0.f,0.f,0.f,0.f},{0.f,0.f,0.f,0.f},
                   {0.f,0.f,0.f,0.f},{0.f,0.f,0.f,0.f}};
  const unsigned short* bp0 = encT + ((size_t)b * HH + hw + r15) * TEE + g * 8;

  for (int k0 = 0; k0 < TEE; k0 += 32) {
    short8 a = {0,0,0,0,0,0,0,0};
    if (r15 < 4) a = *(const short8*)&pe[r15][k0 + g * 8];
    #pragma unroll
    for (int nt = 0; nt < 4; ++nt) {
      short8 bv = *(const short8*)(bp0 + (size_t)nt * 16 * TEE + k0);
      ca[nt] = __builtin_amdgcn_mfma_f32_16x16x32_bf16(a, bv, ca[nt], 0, 0, 0);
    }
  }
  // D rows g*4+r: valid d-rows 0..3 -> only g==0 stores
  if (g == 0) {
    #pragma unroll
    for (int nt = 0; nt < 4; ++nt) {
      float* cp = c_out + ((size_t)(b * TDD) + d0) * HH + hw + nt * 16 + r15;
      #pragma unroll
      for (int r = 0; r < 4; ++r) cp[(size_t)r * HH] = ca[nt][r];
    }
  }
}

extern "C" void kernel_launch(void* const* d_in, const int* in_sizes, int n_in,
                              void* d_out, int out_size, void* d_ws, size_t ws_size,
                              hipStream_t stream) {
  const float* enc = (const float*)d_in[0];
  const float* dec = (const float*)d_in[1];
  const float* Wa  = (const float*)d_in[2];
  const float* Ua  = (const float*)d_in[3];
  const float* Va  = (const float*)d_in[4];

  float* c_out = (float*)d_out;                          // f32 c [B*TD*H]
  float* e_out = c_out + (size_t)BB * TDD * HH;          // f32 e [B*TD*TE]

  float* EW4 = (float*)d_ws;                             // f32 4MB (transposed layout)
  float* EU  = EW4 + (size_t)BB * TEE * HH;              // f32 4MB
  unsigned short* encT = (unsigned short*)(EU + (size_t)BB * TDD * HH);  // bf16 2MB

  prep_proj<<<768, 256, 0, stream>>>(enc, dec, Wa, Ua, EW4, EU, encT);
  fused    <<<512, 512, 0, stream>>>(EW4, EU, Va, encT, c_out, e_out);
}